// Round 9
// baseline (32.057 us; speedup 1.0000x reference)
//
#include <hip/hip_runtime.h>
#include <hip/hip_bf16.h>

typedef float  f32x4  __attribute__((ext_vector_type(4)));
typedef short  bf16x8 __attribute__((ext_vector_type(8)));
typedef short  s16x4  __attribute__((ext_vector_type(4)));

#define NB   64
#define NL1  512
#define NL2  32
#define ND   600
#define NDP  640      // asp LDS row stride in shorts: 80 chunks (mult of 8, XOR-closed)
#define NW1  608      // w1 padded to mult of 32

static __device__ __forceinline__ short f2bf(float f) {
    __hip_bfloat16 h = __float2bfloat16(f);
    return __builtin_bit_cast(short, h);
}

// out[b,i,j] = ctx[b,i,:].w1 + asp[b,j,:].w2 + sum_d ctx[b,i,d]*w3[d]*asp[b,j,d]
//
// 512-thread blocks, 8 waves = 4 row-strips x 2 K-halves. Isolates the
// wave-concurrency variable vs R5 (same per-step VMEM shape, LDS B panel):
// halves per-wave serial K-chain, halves staging, doubles waves/CU to 16.
__global__ __launch_bounds__(512, 2)
void align_kernel(const float* __restrict__ ctx,
                  const float* __restrict__ asp,
                  const float* __restrict__ wu,
                  float* __restrict__ out)
{
    __shared__ short aspw3[NL2 * NDP];    // 40 KB bf16 asp*w3, 16B-chunk XOR swizzle
    __shared__ short w1bf[NW1];           // 1.2 KB bf16 w1 (acc2 broadcast B)
    __shared__ float aspterm[NL2];
    __shared__ float comb[4][64][12];     // 12 KB K-half combine (kh=1 -> kh=0)

    const int tid   = threadIdx.x;
    const int lane  = tid & 63;
    const int w     = tid >> 6;           // wave 0..7
    const int strip = w & 3;              // 16-row strip
    const int kh    = w >> 2;             // K-half
    const int b     = blockIdx.x;         // id%8 = b%8 -> batch-affine XCD
    const int rowbase = blockIdx.y * 64 + strip * 16;

    const int r16 = lane & 15;            // A row / D col
    const int g   = lane >> 4;            // k-subgroup
    const int jx  = lane & 7;

    const float* actx = ctx + ((size_t)b * NL1 + rowbase + r16) * ND + 8 * g;
    const int sbeg = kh ? 10 : 0;
    const int send = kh ? 19 : 10;

    // ctx step-load, nontemporal (read-once stream; skip L2 allocate).
    // t==18, g==3 is the zero K-tail.
#define ISSUE_C(t, C0, C1) do {                                                \
        const int _t = (t);                                                    \
        if (_t < send) {                                                       \
            if (_t <= 17 || g < 3) {                                           \
                C0 = __builtin_nontemporal_load((const f32x4*)(actx + _t * 32));      \
                C1 = __builtin_nontemporal_load((const f32x4*)(actx + _t * 32 + 4));  \
            } else {                                                           \
                C0 = (f32x4){0.f,0.f,0.f,0.f};                                 \
                C1 = (f32x4){0.f,0.f,0.f,0.f};                                 \
            }                                                                  \
        }                                                                      \
    } while (0)

    // prologue: first step's loads issued before (overlapping) staging
    f32x4 v0 = {0.f,0.f,0.f,0.f}, v1 = {0.f,0.f,0.f,0.f};
    ISSUE_C(sbeg, v0, v1);

    // ---- stage w1 as bf16 (zero-padded to 608) ----
    for (int i = tid; i < NW1; i += 512)
        w1bf[i] = (i < ND) ? f2bf(wu[i]) : (short)0;

    // ---- stage asp*w3 (bf16, swizzled) + asp_term: 16 threads per asp row ----
    {
        const int j   = tid >> 4;         // asp row 0..31
        const int sub = tid & 15;
        const int jxs = j & 7;

        if (sub < 8)                      // zero-pad chunk 75 (k=600..607)
            aspw3[j * NDP + ((75 ^ jxs) << 3) + sub] = 0;

        const float* arow = asp + ((size_t)b * NL2 + j) * ND;
        float at = 0.f;
        #pragma unroll
        for (int m = 0; m < 10; ++m) {
            const int k = m * 64 + sub * 4;
            if (k < ND) {
                const float4 v  = *(const float4*)(arow + k);
                const float4 w2 = *(const float4*)(wu + ND + k);
                const float4 w3 = *(const float4*)(wu + 2 * ND + k);
                at += v.x * w2.x + v.y * w2.y + v.z * w2.z + v.w * w2.w;
                s16x4 h;
                h.x = f2bf(v.x * w3.x);
                h.y = f2bf(v.y * w3.y);
                h.z = f2bf(v.z * w3.z);
                h.w = f2bf(v.w * w3.w);
                const int c = (k >> 3) ^ jxs;
                *(s16x4*)&aspw3[j * NDP + (c << 3) + (k & 7)] = h;
            }
        }
        at += __shfl_xor(at, 1);
        at += __shfl_xor(at, 2);
        at += __shfl_xor(at, 4);
        at += __shfl_xor(at, 8);
        if (sub == 0) aspterm[j] = at;
    }
    __syncthreads();

    // ---- main loop: 9-10 steps per wave, depth-1 prefetch ----
    f32x4 acc0 = {0,0,0,0};   // cross, cols 0..15
    f32x4 acc1 = {0,0,0,0};   // cross, cols 16..31
    f32x4 acc2 = {0,0,0,0};   // ctx.w1 (B = w1 broadcast)

    #pragma unroll 1
    for (int s = sbeg; s < send; ++s) {
        f32x4 n0 = {0.f,0.f,0.f,0.f}, n1 = {0.f,0.f,0.f,0.f};
        ISSUE_C(s + 1, n0, n1);

        bf16x8 af;
        af[0] = f2bf(v0.x); af[1] = f2bf(v0.y); af[2] = f2bf(v0.z); af[3] = f2bf(v0.w);
        af[4] = f2bf(v1.x); af[5] = f2bf(v1.y); af[6] = f2bf(v1.z); af[7] = f2bf(v1.w);
        const int cB = ((s * 4 + g) ^ jx) << 3;
        const bf16x8 f0 = *(const bf16x8*)&aspw3[r16 * NDP + cB];
        const bf16x8 f1 = *(const bf16x8*)&aspw3[(16 + r16) * NDP + cB];
        const bf16x8 wf = *(const bf16x8*)&w1bf[s * 32 + 8 * g];
        acc0 = __builtin_amdgcn_mfma_f32_16x16x32_bf16(af, f0, acc0, 0, 0, 0);
        acc1 = __builtin_amdgcn_mfma_f32_16x16x32_bf16(af, f1, acc1, 0, 0, 0);
        acc2 = __builtin_amdgcn_mfma_f32_16x16x32_bf16(af, wf, acc2, 0, 0, 0);

        v0 = n0; v1 = n1;
    }
#undef ISSUE_C

    // ---- K-half combine ----
    if (kh == 1) {
        *(f32x4*)&comb[strip][lane][0] = acc0;
        *(f32x4*)&comb[strip][lane][4] = acc1;
        *(f32x4*)&comb[strip][lane][8] = acc2;
    }
    __syncthreads();
    if (kh == 0) {
        const f32x4 c0s = *(const f32x4*)&comb[strip][lane][0];
        const f32x4 c1s = *(const f32x4*)&comb[strip][lane][4];
        const f32x4 c2s = *(const f32x4*)&comb[strip][lane][8];
        const float atj0 = aspterm[r16];
        const float atj1 = aspterm[16 + r16];
        // D row = g*4 + reg, D col = r16 (verified C/D map, m89)
        float* orow = out + ((size_t)b * NL1 + rowbase + g * 4) * NL2;
        #pragma unroll
        for (int r = 0; r < 4; ++r) {
            const float ct = acc2[r] + c2s[r];
            orow[r * NL2 + r16]      = acc0[r] + c0s[r] + ct + atj0;
            orow[r * NL2 + 16 + r16] = acc1[r] + c1s[r] + ct + atj1;
        }
    }
}

extern "C" void kernel_launch(void* const* d_in, const int* in_sizes, int n_in,
                              void* d_out, int out_size, void* d_ws, size_t ws_size,
                              hipStream_t stream) {
    (void)in_sizes; (void)n_in; (void)d_ws; (void)ws_size; (void)out_size;
    // d_in: [0]=batch_size(int scalar), [1]=ctx f32, [2]=asp f32, [3]=w_u f32
    const float* ctx = (const float*)d_in[1];
    const float* asp = (const float*)d_in[2];
    const float* wu  = (const float*)d_in[3];
    float* out = (float*)d_out;
    dim3 grid(NB, NL1 / 64);
    align_kernel<<<grid, 512, 0, stream>>>(ctx, asp, wu, out);
}